// Round 1
// baseline (3230.542 us; speedup 1.0000x reference)
//
#include <hip/hip_runtime.h>
#include <hip/hip_bf16.h>
#include <cstdint>
#include <cstddef>

using bf16 = __hip_bfloat16;
typedef __attribute__((ext_vector_type(4))) float f32x4;
typedef __attribute__((ext_vector_type(8))) short bf16x8;

#define B_ 128
#define L_ 196
#define T_ 25
#define V_ 10000

__device__ __forceinline__ float b2f(short s) {
  unsigned u = ((unsigned)(unsigned short)s) << 16;
  return __uint_as_float(u);
}
__device__ __forceinline__ bf16 f2b(float f) { return __float2bfloat16(f); }
__device__ __forceinline__ float sigf(float x) { return 1.f / (1.f + __expf(-x)); }
__device__ __forceinline__ float tanh_fast(float x) { return 1.f - 2.f / (1.f + __expf(2.f * x)); }

enum { EPI_F32 = 0, EPI_BF16 = 1, EPI_INIT = 2, EPI_PROJ = 3, EPI_OUT = 4 };

// C = A (MxK, bf16 row-major) @ BT^T (BT is NxK bf16 row-major), + bias.
// Wave tile: (MFRAG*16) x (NFRAG*16); 4 waves along N per block.
template<int MFRAG, int NFRAG, int EPI>
__global__ __launch_bounds__(256) void gemm_bt(
    const bf16* __restrict__ A, const bf16* __restrict__ BT,
    const float* __restrict__ bias, void* __restrict__ Cp,
    const bf16* __restrict__ auxA, float* __restrict__ auxB,
    int M, int N, int K, int ldc)
{
  const int lane = threadIdx.x & 63;
  const int wv = threadIdx.x >> 6;
  const int r16 = lane & 15;
  const int kg = lane >> 4;
  const int m0 = blockIdx.x * (MFRAG * 16);
  const int n0 = blockIdx.y * (NFRAG * 64) + wv * (NFRAG * 16);

  f32x4 acc[MFRAG][NFRAG];
#pragma unroll
  for (int i = 0; i < MFRAG; i++)
#pragma unroll
    for (int j = 0; j < NFRAG; j++) acc[i][j] = f32x4{0.f, 0.f, 0.f, 0.f};

  const bf16* ap = A + (size_t)(m0 + r16) * K + kg * 8;
  const bf16* bp = BT + (size_t)(n0 + r16) * K + kg * 8;

#pragma unroll 4
  for (int k = 0; k < K; k += 32) {
    bf16x8 af[MFRAG], bfr[NFRAG];
#pragma unroll
    for (int i = 0; i < MFRAG; i++)
      af[i] = *(const bf16x8*)(const void*)(ap + (size_t)i * 16 * K + k);
#pragma unroll
    for (int j = 0; j < NFRAG; j++)
      bfr[j] = *(const bf16x8*)(const void*)(bp + (size_t)j * 16 * K + k);
#pragma unroll
    for (int i = 0; i < MFRAG; i++)
#pragma unroll
      for (int j = 0; j < NFRAG; j++)
        acc[i][j] = __builtin_amdgcn_mfma_f32_16x16x32_bf16(af[i], bfr[j], acc[i][j], 0, 0, 0);
  }

#pragma unroll
  for (int i = 0; i < MFRAG; i++)
#pragma unroll
    for (int j = 0; j < NFRAG; j++)
#pragma unroll
      for (int r = 0; r < 4; r++) {
        int m = m0 + i * 16 + kg * 4 + r;
        int n = n0 + j * 16 + r16;
        if (n >= N) continue;
        float v = acc[i][j][r] + bias[n];
        if constexpr (EPI == EPI_F32) {
          ((float*)Cp)[(size_t)m * ldc + n] = v;
        } else if constexpr (EPI == EPI_BF16) {
          ((bf16*)Cp)[(size_t)m * ldc + n] = f2b(v);
        } else if constexpr (EPI == EPI_INIT) {
          float tv = tanhf(v);
          if (n < 512) ((bf16*)Cp)[(size_t)m * ldc + n] = f2b(tv);   // h0 -> A1[0] h-slot
          else auxB[(size_t)m * 512 + (n - 512)] = tv;               // c0 (f32)
        } else if constexpr (EPI == EPI_PROJ) {
          v += __bfloat162float(auxA[(size_t)m * 1024 + n]);         // + x (bf16)
          ((bf16*)Cp)[(size_t)m * ldc + n] = f2b(v);
        } else {  // EPI_OUT
          ((float*)Cp)[(size_t)m * ldc + n] = v;
        }
      }
}

// dst (nrows x kt, bf16) = transpose of [top; bot] with zero-padding for rows >= ncols.
__global__ void trans_cat(const float* __restrict__ top, const float* __restrict__ bot,
                          bf16* __restrict__ dst, int ncols, long total, int ktop, int kt)
{
  for (long idx = (long)blockIdx.x * blockDim.x + threadIdx.x; idx < total;
       idx += (long)gridDim.x * blockDim.x) {
    int n = (int)(idx / kt), k = (int)(idx % kt);
    float v = 0.f;
    if (n < ncols) {
      if (k < ktop) { if (top) v = top[(size_t)k * ncols + n]; }
      else if (bot) { v = bot[(size_t)(k - ktop) * ncols + n]; }
    }
    dst[idx] = f2b(v);
  }
}

__global__ void bias_comb(const float* __restrict__ b_lstm, const float* __restrict__ b_s,
                          const float* __restrict__ b_g, const float* __restrict__ b_sa,
                          const float* __restrict__ b_Lh, const float* __restrict__ b_Lz,
                          const float* __restrict__ b_ih, const float* __restrict__ b_ic,
                          float* __restrict__ bg, float* __restrict__ ba,
                          float* __restrict__ bp, float* __restrict__ bi)
{
  int i = blockIdx.x * blockDim.x + threadIdx.x;
  if (i < 2560) bg[i] = (i < 2048) ? b_lstm[i] : b_s[i - 2048];
  if (i < 1024) ba[i] = (i < 512) ? b_g[i] : b_sa[i - 512];
  if (i < 512)  bp[i] = b_Lh[i] + b_Lz[i];
  if (i < 1024) bi[i] = (i < 512) ? b_ih[i] : b_ic[i - 512];
}

__global__ void conv_bf16(const float* __restrict__ src, bf16* __restrict__ dst, long n)
{
  for (long i = (long)blockIdx.x * blockDim.x + threadIdx.x; i < n;
       i += (long)gridDim.x * blockDim.x)
    dst[i] = f2b(src[i]);
}

__global__ __launch_bounds__(512) void mean_enc(const float* __restrict__ enc,
                                                bf16* __restrict__ mb)
{
  int b = blockIdx.x, c = threadIdx.x;
  float s = 0.f;
  for (int l = 0; l < L_; l++) s += enc[((size_t)b * L_ + l) * 512 + c];
  mb[b * 512 + c] = f2b(s * (1.f / (float)L_));
}

__global__ void gather_x(const float* __restrict__ emb, const int* __restrict__ caps,
                         bf16* __restrict__ A1)
{
  int tb = blockIdx.x;          // t*128 + b
  int t = tb >> 7, b = tb & 127;
  int word = caps[b * 26 + t];
  const float* src = emb + (size_t)word * 512 + threadIdx.x * 8;
  bf16* dst = A1 + (size_t)t * (128 * 1024) + b * 1024 + threadIdx.x * 8;
#pragma unroll
  for (int j = 0; j < 8; j++) dst[j] = f2b(src[j]);
}

__global__ __launch_bounds__(512) void lstm_pw(
    const float* __restrict__ gates, float* __restrict__ c, float* __restrict__ s_f32,
    bf16* __restrict__ A1h_next, bf16* __restrict__ Aag, bf16* __restrict__ Aproj)
{
  int b = blockIdx.x, d = threadIdx.x;
  const float* g = gates + (size_t)b * 2560;
  float gi = g[d], gf = g[512 + d], gg = g[1024 + d], go = g[1536 + d], gxs = g[2048 + d];
  float cn = sigf(gf) * c[b * 512 + d] + sigf(gi) * tanh_fast(gg);
  float tcn = tanh_fast(cn);
  float hn = sigf(go) * tcn;
  float ss = sigf(gxs) * tcn;
  c[b * 512 + d] = cn;
  s_f32[b * 512 + d] = ss;
  bf16 hb = f2b(hn), sb = f2b(ss);
  Aag[b * 1024 + d] = hb;
  Aag[b * 1024 + 512 + d] = sb;
  Aproj[b * 1024 + d] = hb;
  if (A1h_next) A1h_next[b * 1024 + d] = hb;   // ptr pre-offset by +512 (h-slot)
}

__global__ __launch_bounds__(256) void att_step(
    const float* __restrict__ agsw, const bf16* __restrict__ attv,
    const bf16* __restrict__ enc, const float* __restrict__ w_a,
    const float* __restrict__ s_f32, const int* __restrict__ cap_len,
    float* __restrict__ alphas_out, float* __restrict__ betas_out,
    bf16* __restrict__ Aproj_ctx, int t)
{
  __shared__ float sh_e[197];
  __shared__ float sh_a[197];
  int b = blockIdx.x, tid = threadIdx.x;
  int wv = tid >> 6, lane = tid & 63;
  const float* ag = agsw + b * 1024;
  float ag8[8], wa8[8];
  int a0 = lane * 8;
#pragma unroll
  for (int j = 0; j < 8; j++) { ag8[j] = ag[a0 + j]; wa8[j] = w_a[a0 + j]; }

  for (int jb = wv; jb < 197; jb += 4) {
    float part = 0.f;
    if (jb < 196) {
      bf16x8 av = *(const bf16x8*)(const void*)(attv + ((size_t)b * L_ + jb) * 512 + a0);
#pragma unroll
      for (int j = 0; j < 8; j++) part += wa8[j] * tanh_fast(b2f(av[j]) + ag8[j]);
    } else {
      const float* sw = ag + 512;
#pragma unroll
      for (int j = 0; j < 8; j++) part += wa8[j] * tanh_fast(sw[a0 + j] + ag8[j]);
    }
#pragma unroll
    for (int off = 32; off >= 1; off >>= 1) part += __shfl_xor(part, off, 64);
    if (lane == 0) sh_e[jb] = part;
  }
  __syncthreads();

  if (wv == 0) {
    float ev[4];
    float m = -1e30f;
#pragma unroll
    for (int i = 0; i < 4; i++) {
      int jb = lane + i * 64;
      ev[i] = (jb < 197) ? sh_e[jb] : -1e30f;
      m = fmaxf(m, ev[i]);
    }
#pragma unroll
    for (int off = 32; off >= 1; off >>= 1) m = fmaxf(m, __shfl_xor(m, off, 64));
    float ssum = 0.f;
#pragma unroll
    for (int i = 0; i < 4; i++) {
      int jb = lane + i * 64;
      ev[i] = (jb < 197) ? __expf(ev[i] - m) : 0.f;
      ssum += ev[i];
    }
#pragma unroll
    for (int off = 32; off >= 1; off >>= 1) ssum += __shfl_xor(ssum, off, 64);
    float inv = 1.f / ssum;
#pragma unroll
    for (int i = 0; i < 4; i++) {
      int jb = lane + i * 64;
      if (jb < 197) sh_a[jb] = ev[i] * inv;
    }
  }
  __syncthreads();

  float beta = sh_a[196];
  int dec = cap_len[b] - 1; if (dec < 1) dec = 1;
  float act = (t < dec) ? 1.f : 0.f;
  if (tid < 196) alphas_out[(size_t)b * (T_ * L_) + t * L_ + tid] = sh_a[tid] * act;
  if (tid == 196) betas_out[b * T_ + t] = beta * act;

  // ctx = sum_l alpha_l * enc[b,l,:] + beta * s ; write bf16 into Aproj ctx-slot
  int c0 = tid * 2;
  float cx0 = 0.f, cx1 = 0.f;
  const unsigned* ep = (const unsigned*)(const void*)enc + (((size_t)b * L_) * 512 + c0) / 2;
  for (int l = 0; l < L_; l++) {
    float al = sh_a[l];
    unsigned pv = ep[(size_t)l * 256];
    cx0 += al * b2f((short)(pv & 0xffff));
    cx1 += al * b2f((short)(pv >> 16));
  }
  cx0 += beta * s_f32[b * 512 + c0];
  cx1 += beta * s_f32[b * 512 + c0 + 1];
  Aproj_ctx[b * 1024 + 512 + c0] = f2b(cx0);
  Aproj_ctx[b * 1024 + 512 + c0 + 1] = f2b(cx1);
}

extern "C" void kernel_launch(void* const* d_in, const int* in_sizes, int n_in,
                              void* d_out, int out_size, void* d_ws, size_t ws_size,
                              hipStream_t stream)
{
  const float* enc      = (const float*)d_in[0];
  const int*   caps     = (const int*)d_in[1];
  const int*   clen     = (const int*)d_in[2];
  const float* emb      = (const float*)d_in[3];
  const float* W_ih     = (const float*)d_in[4];
  const float* W_hh     = (const float*)d_in[5];
  const float* b_lstm   = (const float*)d_in[6];
  const float* Wx_s     = (const float*)d_in[7];
  const float* Wh_s     = (const float*)d_in[8];
  const float* b_s      = (const float*)d_in[9];
  const float* W_v      = (const float*)d_in[10];
  const float* b_v      = (const float*)d_in[11];
  const float* W_g      = (const float*)d_in[12];
  const float* b_g      = (const float*)d_in[13];
  const float* W_s_att  = (const float*)d_in[14];
  const float* b_sa     = (const float*)d_in[15];
  const float* w_a      = (const float*)d_in[16];
  const float* W_init_h = (const float*)d_in[17];
  const float* b_init_h = (const float*)d_in[18];
  const float* W_init_c = (const float*)d_in[19];
  const float* b_init_c = (const float*)d_in[20];
  const float* W_Lh     = (const float*)d_in[21];
  const float* b_Lh     = (const float*)d_in[22];
  const float* W_Lz     = (const float*)d_in[23];
  const float* b_Lz     = (const float*)d_in[24];
  const float* W_Lo     = (const float*)d_in[25];
  const float* b_Lo     = (const float*)d_in[26];

  float* preds  = (float*)d_out;
  float* alphas = preds + (size_t)B_ * T_ * V_;
  float* betas  = alphas + (size_t)B_ * T_ * L_;

  char* ws = (char*)d_ws;
  size_t off = 0;
  auto alloc = [&](size_t bytes) -> void* {
    void* p = ws + off;
    off = (off + bytes + 255) & ~(size_t)255;
    return p;
  };
  bf16*  enc_b  = (bf16*)alloc((size_t)B_ * L_ * 512 * 2);
  bf16*  attv_b = (bf16*)alloc((size_t)B_ * L_ * 512 * 2);
  bf16*  WT_g   = (bf16*)alloc((size_t)2560 * 1024 * 2);
  bf16*  WT_a   = (bf16*)alloc((size_t)1024 * 1024 * 2);
  bf16*  WT_p   = (bf16*)alloc((size_t)512 * 1024 * 2);
  bf16*  WT_lo  = (bf16*)alloc((size_t)10240 * 512 * 2);
  bf16*  WT_v   = (bf16*)alloc((size_t)512 * 512 * 2);
  bf16*  WT_i   = (bf16*)alloc((size_t)1024 * 512 * 2);
  float* bgx    = (float*)alloc(2560 * 4);
  float* bax    = (float*)alloc(1024 * 4);
  float* bpx    = (float*)alloc(512 * 4);
  float* bix    = (float*)alloc(1024 * 4);
  bf16*  mean_b = (bf16*)alloc(128 * 512 * 2);
  bf16*  A1     = (bf16*)alloc((size_t)T_ * 128 * 1024 * 2);
  float* gatesb = (float*)alloc((size_t)128 * 2560 * 4);
  float* agswb  = (float*)alloc((size_t)128 * 1024 * 4);
  bf16*  Aag    = (bf16*)alloc(128 * 1024 * 2);
  bf16*  Aproj  = (bf16*)alloc(128 * 1024 * 2);
  bf16*  projb  = (bf16*)alloc(128 * 512 * 2);
  float* cbuf   = (float*)alloc(128 * 512 * 4);
  float* sbuf   = (float*)alloc(128 * 512 * 4);
  if (off > ws_size) return;  // workspace too small -> loud validation failure

  // ---- prep (runs every call; deterministic) ----
  bias_comb<<<dim3(10), dim3(256), 0, stream>>>(b_lstm, b_s, b_g, b_sa, b_Lh, b_Lz,
                                                b_init_h, b_init_c, bgx, bax, bpx, bix);
  auto T2 = [&](const float* top, const float* bot, bf16* dst, int ncols, int nrows,
                int ktop, int kbot) {
    int kt = ktop + kbot;
    long total = (long)nrows * kt;
    int blocks = (int)((total + 2047) / 2048);
    if (blocks > 4096) blocks = 4096;
    trans_cat<<<dim3(blocks), dim3(256), 0, stream>>>(top, bot, dst, ncols, total, ktop, kt);
  };
  T2(W_ih, W_hh, WT_g, 2048, 2048, 512, 512);
  T2(Wx_s, Wh_s, WT_g + (size_t)2048 * 1024, 512, 512, 512, 512);
  T2(W_g, nullptr, WT_a, 512, 512, 512, 512);
  T2(nullptr, W_s_att, WT_a + (size_t)512 * 1024, 512, 512, 512, 512);
  T2(W_Lh, W_Lz, WT_p, 512, 512, 512, 512);
  T2(W_Lo, nullptr, WT_lo, 10000, 10240, 512, 0);
  T2(W_v, nullptr, WT_v, 512, 512, 512, 0);
  T2(W_init_h, nullptr, WT_i, 512, 512, 512, 0);
  T2(W_init_c, nullptr, WT_i + (size_t)512 * 512, 512, 512, 512, 0);
  conv_bf16<<<dim3(8192), dim3(256), 0, stream>>>(enc, enc_b, (long)B_ * L_ * 512);
  mean_enc<<<dim3(128), dim3(512), 0, stream>>>(enc, mean_b);
  gather_x<<<dim3(T_ * 128), dim3(64), 0, stream>>>(emb, caps, A1);

  // h0 -> A1[0] h-slot (bf16), c0 -> cbuf (f32)
  gemm_bt<1, 4, EPI_INIT><<<dim3(8, 4), dim3(256), 0, stream>>>(
      mean_b, WT_i, bix, (void*)(A1 + 512), nullptr, cbuf, 128, 1024, 512, 1024);
  // att_v = enc @ W_v + b_v   (bf16)
  gemm_bt<4, 2, EPI_BF16><<<dim3(392, 4), dim3(256), 0, stream>>>(
      enc_b, WT_v, b_v, attv_b, nullptr, nullptr, B_ * L_, 512, 512, 512);

  for (int t = 0; t < T_; t++) {
    bf16* A1t = A1 + (size_t)t * 128 * 1024;
    // gates|xs = [x|h] @ [W_ih;W_hh | Wx_s;Wh_s] + [b_lstm|b_s]
    gemm_bt<1, 4, EPI_F32><<<dim3(8, 10), dim3(256), 0, stream>>>(
        A1t, WT_g, bgx, gatesb, nullptr, nullptr, 128, 2560, 1024, 2560);
    bf16* A1next = (t < T_ - 1) ? (A1 + (size_t)(t + 1) * 128 * 1024 + 512) : nullptr;
    lstm_pw<<<dim3(128), dim3(512), 0, stream>>>(gatesb, cbuf, sbuf, A1next, Aag, Aproj);
    // [ag | sW] = [h_new|s] @ blockdiag(W_g, W_s_att) + [b_g|b_sa]
    gemm_bt<1, 2, EPI_F32><<<dim3(8, 8), dim3(256), 0, stream>>>(
        Aag, WT_a, bax, agswb, nullptr, nullptr, 128, 1024, 1024, 1024);
    att_step<<<dim3(128), dim3(256), 0, stream>>>(
        agswb, attv_b, enc_b, w_a, sbuf, clen, alphas, betas, Aproj, t);
    // proj = x + h@W_Lh + ctx@W_Lz + b  (bf16)
    gemm_bt<1, 2, EPI_PROJ><<<dim3(8, 4), dim3(256), 0, stream>>>(
        Aproj, WT_p, bpx, projb, A1t, nullptr, 128, 512, 1024, 512);
    // preds[:,t,:] = proj @ W_Lo + b_Lo
    gemm_bt<1, 4, EPI_OUT><<<dim3(8, 40), dim3(256), 0, stream>>>(
        projb, WT_lo, b_Lo, preds + (size_t)t * V_, nullptr, nullptr, 128, V_, 512, T_ * V_);
  }
}

// Round 3
// 1913.474 us; speedup vs baseline: 1.6883x; 1.6883x over previous
//
#include <hip/hip_runtime.h>
#include <hip/hip_bf16.h>
#include <cstdint>
#include <cstddef>

using bf16 = __hip_bfloat16;
typedef __attribute__((ext_vector_type(4))) float f32x4;
typedef __attribute__((ext_vector_type(8))) short bf16x8;

#define B_ 128
#define L_ 196
#define T_ 25
#define V_ 10000

__device__ __forceinline__ float b2f(short s) {
  unsigned u = ((unsigned)(unsigned short)s) << 16;
  return __uint_as_float(u);
}
__device__ __forceinline__ bf16 f2b(float f) { return __float2bfloat16(f); }
__device__ __forceinline__ short f2bs(float f) {
  return __builtin_bit_cast(short, __float2bfloat16(f));
}
__device__ __forceinline__ float sigf(float x) { return 1.f / (1.f + __expf(-x)); }
__device__ __forceinline__ float tanh_fast(float x) { return 1.f - 2.f / (1.f + __expf(2.f * x)); }

// Fragment-packed layout: 16x32 tiles, tile-row-major; within a tile element
// (r, c) lives at (((rt*KT + kt)*64 + ((c&31)>>3)*16 + r)*8 + (c&7)).
// A wave's MFMA fragment (rows r16, cols kg*8+j) is then base + lane*8 elems,
// i.e. one contiguous 1KiB load per fragment.
__device__ __forceinline__ size_t pidx(int row, int col, int K) {
  int KT = K >> 5;
  return (((size_t)(row >> 4) * KT + (col >> 5)) * 64 +
          (size_t)(((col & 31) >> 3) * 16 + (row & 15))) * 8 + (col & 7);
}

enum { EPI_F32 = 0, EPI_BF16 = 1, EPI_INIT = 2, EPI_PROJ = 3, EPI_OUT = 4 };

// C = A (MxK packed) @ BT^T (BT: NxK packed), + bias.
template<int MFRAG, int NFRAG, int EPI>
__global__ __launch_bounds__(256) void gemm_pk(
    const bf16* __restrict__ A, const bf16* __restrict__ BT,
    const float* __restrict__ bias, void* __restrict__ Cp,
    const bf16* __restrict__ auxA, float* __restrict__ auxB,
    int M, int N, int K, int ldc, int R0)
{
  const int lane = threadIdx.x & 63;
  const int wv = threadIdx.x >> 6;
  const int r16 = lane & 15;
  const int kg = lane >> 4;
  const int m0 = blockIdx.x * (MFRAG * 16);
  const int n0 = blockIdx.y * (NFRAG * 64) + wv * (NFRAG * 16);
  const int KT = K >> 5;

  f32x4 acc[MFRAG][NFRAG];
#pragma unroll
  for (int i = 0; i < MFRAG; i++)
#pragma unroll
    for (int j = 0; j < NFRAG; j++) acc[i][j] = f32x4{0.f, 0.f, 0.f, 0.f};

  const bf16* ap = A + (size_t)(m0 >> 4) * KT * 512 + lane * 8;
  const bf16* bp = BT + (size_t)(n0 >> 4) * KT * 512 + lane * 8;

#pragma unroll 4
  for (int kt = 0; kt < KT; kt++) {
    bf16x8 af[MFRAG], bfr[NFRAG];
#pragma unroll
    for (int i = 0; i < MFRAG; i++)
      af[i] = *(const bf16x8*)(const void*)(ap + ((size_t)i * KT + kt) * 512);
#pragma unroll
    for (int j = 0; j < NFRAG; j++)
      bfr[j] = *(const bf16x8*)(const void*)(bp + ((size_t)j * KT + kt) * 512);
#pragma unroll
    for (int i = 0; i < MFRAG; i++)
#pragma unroll
      for (int j = 0; j < NFRAG; j++)
        acc[i][j] = __builtin_amdgcn_mfma_f32_16x16x32_bf16(af[i], bfr[j], acc[i][j], 0, 0, 0);
  }

#pragma unroll
  for (int i = 0; i < MFRAG; i++)
#pragma unroll
    for (int j = 0; j < NFRAG; j++)
#pragma unroll
      for (int r = 0; r < 4; r++) {
        int m = m0 + i * 16 + kg * 4 + r;
        int n = n0 + j * 16 + r16;
        if (n >= N) continue;
        float v = acc[i][j][r] + bias[n];
        if constexpr (EPI == EPI_F32) {
          ((float*)Cp)[(size_t)m * ldc + n] = v;
        } else if constexpr (EPI == EPI_BF16) {
          ((bf16*)Cp)[(size_t)m * ldc + n] = f2b(v);
        } else if constexpr (EPI == EPI_INIT) {
          float tv = tanhf(v);
          if (n < 512) ((bf16*)Cp)[pidx(m, 512 + n, 1024)] = f2b(tv);  // h0 -> A1[0]
          else auxB[(size_t)m * 512 + (n - 512)] = tv;                 // c0 (f32)
        } else if constexpr (EPI == EPI_PROJ) {
          v += b2f(((const short*)auxA)[pidx(m, n, 1024)]);            // + x
          ((bf16*)Cp)[pidx(R0 + m, n, 512)] = f2b(v);                  // packed projb
        } else {  // EPI_OUT: preds[b, t, n], row = t*128+b
          int t = m >> 7, b = m & 127;
          ((float*)Cp)[(size_t)b * (T_ * V_) + (size_t)t * V_ + n] = v;
        }
      }
}

// Packed-transpose: dst (nrows x K packed) = [top; bot]^T with zero padding.
__global__ void trans_pack(const float* __restrict__ top, const float* __restrict__ bot,
                           bf16* __restrict__ dst, int ncols, long nElem8, int ktop, int K)
{
  int KT = K >> 5;
  for (long t8 = (long)blockIdx.x * blockDim.x + threadIdx.x; t8 < nElem8;
       t8 += (long)gridDim.x * blockDim.x) {
    int r = (int)(t8 & 15);
    int kg = (int)((t8 >> 4) & 3);
    long tile = t8 >> 6;
    int kt = (int)(tile % KT);
    int rt = (int)(tile / KT);
    int n = rt * 16 + r;
    int kb = kt * 32 + kg * 8;
    bf16x8 out;
#pragma unroll
    for (int j = 0; j < 8; j++) {
      int k = kb + j;
      float v = 0.f;
      if (n < ncols) {
        if (k < ktop) { if (top) v = top[(size_t)k * ncols + n]; }
        else if (bot) { v = bot[(size_t)(k - ktop) * ncols + n]; }
      }
      out[j] = f2bs(v);
    }
    *(bf16x8*)(void*)(dst + t8 * 8) = out;
  }
}

// enc (f32 row-major, 25088x512) -> enc_p (bf16 packed)
__global__ void conv_pack(const float* __restrict__ src, bf16* __restrict__ dst, long nElem8)
{
  for (long t8 = (long)blockIdx.x * blockDim.x + threadIdx.x; t8 < nElem8;
       t8 += (long)gridDim.x * blockDim.x) {
    int r = (int)(t8 & 15);
    int kg = (int)((t8 >> 4) & 3);
    long tile = t8 >> 6;
    int kt = (int)(tile & 15);           // KT = 16 (K=512)
    int rt = (int)(tile >> 4);
    const float* s = src + ((size_t)(rt * 16 + r)) * 512 + kt * 32 + kg * 8;
    bf16x8 out;
#pragma unroll
    for (int j = 0; j < 8; j++) out[j] = f2bs(s[j]);
    *(bf16x8*)(void*)(dst + t8 * 8) = out;
  }
}

__global__ void bias_comb(const float* __restrict__ b_lstm, const float* __restrict__ b_s,
                          const float* __restrict__ b_g, const float* __restrict__ b_sa,
                          const float* __restrict__ b_Lh, const float* __restrict__ b_Lz,
                          const float* __restrict__ b_ih, const float* __restrict__ b_ic,
                          float* __restrict__ bg, float* __restrict__ ba,
                          float* __restrict__ bp, float* __restrict__ bi)
{
  int i = blockIdx.x * blockDim.x + threadIdx.x;
  if (i < 2560) bg[i] = (i < 2048) ? b_lstm[i] : b_s[i - 2048];
  if (i < 1024) ba[i] = (i < 512) ? b_g[i] : b_sa[i - 512];
  if (i < 512)  bp[i] = b_Lh[i] + b_Lz[i];
  if (i < 1024) bi[i] = (i < 512) ? b_ih[i] : b_ic[i - 512];
}

__global__ __launch_bounds__(512) void mean_enc(const float* __restrict__ enc,
                                                bf16* __restrict__ mb)
{
  int b = blockIdx.x, c = threadIdx.x;
  float s = 0.f;
  for (int l = 0; l < L_; l++) s += enc[((size_t)b * L_ + l) * 512 + c];
  mb[pidx(b, c, 512)] = f2b(s * (1.f / (float)L_));
}

__global__ void gather_x(const float* __restrict__ emb, const int* __restrict__ caps,
                         bf16* __restrict__ A1)
{
  int tb = blockIdx.x;          // t*128 + b
  int t = tb >> 7, b = tb & 127;
  int word = caps[b * 26 + t];
  int c0 = threadIdx.x * 8;
  const float* src = emb + (size_t)word * 512 + c0;
  bf16* dst = A1 + (size_t)t * (128 * 1024) + pidx(b, c0, 1024);
  bf16x8 out;
#pragma unroll
  for (int j = 0; j < 8; j++) out[j] = f2bs(src[j]);
  *(bf16x8*)(void*)dst = out;
}

__global__ __launch_bounds__(512) void lstm_pw(
    const float* __restrict__ gates, float* __restrict__ c, float* __restrict__ s_f32,
    bf16* __restrict__ A1next, bf16* __restrict__ Aag, bf16* __restrict__ Aproj)
{
  int b = blockIdx.x, d = threadIdx.x;
  const float* g = gates + (size_t)b * 2560;
  float gi = g[d], gf = g[512 + d], gg = g[1024 + d], go = g[1536 + d], gxs = g[2048 + d];
  float cn = sigf(gf) * c[b * 512 + d] + sigf(gi) * tanh_fast(gg);
  float tcn = tanh_fast(cn);
  float hn = sigf(go) * tcn;
  float ss = sigf(gxs) * tcn;
  c[b * 512 + d] = cn;
  s_f32[b * 512 + d] = ss;
  bf16 hb = f2b(hn), sb = f2b(ss);
  size_t plo = pidx(b, d, 1024), phi = pidx(b, 512 + d, 1024);
  Aag[plo] = hb;
  Aag[phi] = sb;
  Aproj[plo] = hb;
  if (A1next) A1next[phi] = hb;
}

// e[b,l] = w_a . tanh(attv[b,l,:] + ag[b,:]); e[b,196] = w_a . tanh(sW[b,:] + ag[b,:])
__global__ __launch_bounds__(256) void att_e(
    const bf16* __restrict__ attv, const float* __restrict__ agsw,
    const float* __restrict__ w_a, float* __restrict__ ebuf)
{
  int lane = threadIdx.x & 63;
  int gw = blockIdx.x * 4 + (threadIdx.x >> 6);
  int a0 = lane * 8;
  float wa8[8];
#pragma unroll
  for (int j = 0; j < 8; j++) wa8[j] = w_a[a0 + j];
  int row0 = gw * 16;
  for (int i = 0; i < 16; i++) {
    int row = row0 + i;
    float part = 0.f;
    int b, l;
    if (row < B_ * L_) { b = row / L_; l = row - b * L_; }
    else { b = row - B_ * L_; l = L_; }
    const float* ag = agsw + b * 1024;
    if (l < L_) {
      bf16x8 av = *(const bf16x8*)(const void*)(attv + ((size_t)b * L_ + l) * 512 + a0);
#pragma unroll
      for (int j = 0; j < 8; j++) part += wa8[j] * tanh_fast(b2f(av[j]) + ag[a0 + j]);
    } else {
#pragma unroll
      for (int j = 0; j < 8; j++) part += wa8[j] * tanh_fast(ag[512 + a0 + j] + ag[a0 + j]);
    }
#pragma unroll
    for (int off = 32; off >= 1; off >>= 1) part += __shfl_xor(part, off, 64);
    if (lane == 0) ebuf[b * 200 + l] = part;
  }
}

// softmax over e[b,0..197) + ctx partial channels + alphas/betas output
__global__ __launch_bounds__(128) void att_ctx(
    const float* __restrict__ ebuf, const bf16* __restrict__ enc_p,
    const float* __restrict__ s_f32, const int* __restrict__ cap_len,
    float* __restrict__ alphas_out, float* __restrict__ betas_out,
    bf16* __restrict__ Aproj_ctx, int t)
{
  __shared__ float sh_a[256];
  __shared__ float redm[2], reds[2];
  int b = blockIdx.x, cs = blockIdx.y, tid = threadIdx.x;
  int wv = tid >> 6, lane = tid & 63;
  const float* e = ebuf + b * 200;
  float v0 = (tid < 197) ? e[tid] : -1e30f;
  float v1 = (tid + 128 < 197) ? e[tid + 128] : -1e30f;
  float m = fmaxf(v0, v1);
#pragma unroll
  for (int off = 32; off >= 1; off >>= 1) m = fmaxf(m, __shfl_xor(m, off, 64));
  if (lane == 0) redm[wv] = m;
  __syncthreads();
  m = fmaxf(redm[0], redm[1]);
  float p0 = (tid < 197) ? __expf(v0 - m) : 0.f;
  float p1 = (tid + 128 < 197) ? __expf(v1 - m) : 0.f;
  float s = p0 + p1;
#pragma unroll
  for (int off = 32; off >= 1; off >>= 1) s += __shfl_xor(s, off, 64);
  if (lane == 0) reds[wv] = s;
  __syncthreads();
  float inv = 1.f / (reds[0] + reds[1]);
  sh_a[tid] = p0 * inv;
  sh_a[tid + 128] = p1 * inv;
  __syncthreads();

  float beta = sh_a[196];
  int dec = cap_len[b] - 1; if (dec < 1) dec = 1;
  float act = (t < dec) ? 1.f : 0.f;
  if (cs == 0) {
    if (tid < 196) alphas_out[(size_t)b * (T_ * L_) + t * L_ + tid] = sh_a[tid] * act;
    if (tid + 128 < 196) alphas_out[(size_t)b * (T_ * L_) + t * L_ + tid + 128] = sh_a[tid + 128] * act;
    if (tid == 0) betas_out[b * T_ + t] = beta * act;
  }

  int c0 = cs * 256 + tid * 2;
  float cx0 = 0.f, cx1 = 0.f;
  int row0 = b * L_;
  for (int l = 0; l < L_; l++) {
    float al = sh_a[l];
    unsigned pv = *(const unsigned*)(const void*)(enc_p + pidx(row0 + l, c0, 512));
    cx0 += al * b2f((short)(pv & 0xffff));
    cx1 += al * b2f((short)(pv >> 16));
  }
  cx0 += beta * s_f32[b * 512 + c0];
  cx1 += beta * s_f32[b * 512 + c0 + 1];
  size_t po = pidx(b, 512 + c0, 1024);
  Aproj_ctx[po] = f2b(cx0);
  Aproj_ctx[po + 1] = f2b(cx1);
}

extern "C" void kernel_launch(void* const* d_in, const int* in_sizes, int n_in,
                              void* d_out, int out_size, void* d_ws, size_t ws_size,
                              hipStream_t stream)
{
  const float* enc      = (const float*)d_in[0];
  const int*   caps     = (const int*)d_in[1];
  const int*   clen     = (const int*)d_in[2];
  const float* emb      = (const float*)d_in[3];
  const float* W_ih     = (const float*)d_in[4];
  const float* W_hh     = (const float*)d_in[5];
  const float* b_lstm   = (const float*)d_in[6];
  const float* Wx_s     = (const float*)d_in[7];
  const float* Wh_s     = (const float*)d_in[8];
  const float* b_s      = (const float*)d_in[9];
  const float* W_v      = (const float*)d_in[10];
  const float* b_v      = (const float*)d_in[11];
  const float* W_g      = (const float*)d_in[12];
  const float* b_g      = (const float*)d_in[13];
  const float* W_s_att  = (const float*)d_in[14];
  const float* b_sa     = (const float*)d_in[15];
  const float* w_a      = (const float*)d_in[16];
  const float* W_init_h = (const float*)d_in[17];
  const float* b_init_h = (const float*)d_in[18];
  const float* W_init_c = (const float*)d_in[19];
  const float* b_init_c = (const float*)d_in[20];
  const float* W_Lh     = (const float*)d_in[21];
  const float* b_Lh     = (const float*)d_in[22];
  const float* W_Lz     = (const float*)d_in[23];
  const float* b_Lz     = (const float*)d_in[24];
  const float* W_Lo     = (const float*)d_in[25];
  const float* b_Lo     = (const float*)d_in[26];

  float* preds  = (float*)d_out;
  float* alphas = preds + (size_t)B_ * T_ * V_;
  float* betas  = alphas + (size_t)B_ * T_ * L_;

  char* ws = (char*)d_ws;
  size_t off = 0;
  auto alloc = [&](size_t bytes) -> void* {
    void* p = ws + off;
    off = (off + bytes + 255) & ~(size_t)255;
    return p;
  };
  bf16*  enc_p  = (bf16*)alloc((size_t)B_ * L_ * 512 * 2);
  bf16*  attv_b = (bf16*)alloc((size_t)B_ * L_ * 512 * 2);
  bf16*  WT_g   = (bf16*)alloc((size_t)2560 * 1024 * 2);
  bf16*  WT_a   = (bf16*)alloc((size_t)1024 * 1024 * 2);
  bf16*  WT_p   = (bf16*)alloc((size_t)512 * 1024 * 2);
  bf16*  WT_lo  = (bf16*)alloc((size_t)10240 * 512 * 2);
  bf16*  WT_v   = (bf16*)alloc((size_t)512 * 512 * 2);
  bf16*  WT_i   = (bf16*)alloc((size_t)1024 * 512 * 2);
  float* bgx    = (float*)alloc(2560 * 4);
  float* bax    = (float*)alloc(1024 * 4);
  float* bpx    = (float*)alloc(512 * 4);
  float* bix    = (float*)alloc(1024 * 4);
  bf16*  mean_b = (bf16*)alloc(128 * 512 * 2);
  bf16*  A1     = (bf16*)alloc((size_t)T_ * 128 * 1024 * 2);
  float* gatesb = (float*)alloc((size_t)128 * 2560 * 4);
  float* agswb  = (float*)alloc((size_t)128 * 1024 * 4);
  bf16*  Aag    = (bf16*)alloc(128 * 1024 * 2);
  bf16*  Aproj  = (bf16*)alloc(128 * 1024 * 2);
  bf16*  projb  = (bf16*)alloc((size_t)T_ * 128 * 512 * 2);
  float* cbuf   = (float*)alloc(128 * 512 * 4);
  float* sbuf   = (float*)alloc(128 * 512 * 4);
  float* ebuf   = (float*)alloc(128 * 200 * 4);
  if (off > ws_size) return;  // loud validation failure if ws too small

  // ---- prep ----
  bias_comb<<<dim3(10), dim3(256), 0, stream>>>(b_lstm, b_s, b_g, b_sa, b_Lh, b_Lz,
                                                b_init_h, b_init_c, bgx, bax, bpx, bix);
  auto TP = [&](const float* top, const float* bot, bf16* dst, int ncols, int nrows,
                int ktop, int K) {
    long n8 = (long)nrows * K / 8;
    int blocks = (int)((n8 + 255) / 256);
    if (blocks > 4096) blocks = 4096;
    trans_pack<<<dim3(blocks), dim3(256), 0, stream>>>(top, bot, dst, ncols, n8, ktop, K);
  };
  TP(W_ih, W_hh, WT_g, 2048, 2048, 512, 1024);
  TP(Wx_s, Wh_s, WT_g + (size_t)2048 * 1024, 512, 512, 512, 1024);
  TP(W_g, nullptr, WT_a, 512, 512, 512, 1024);
  TP(nullptr, W_s_att, WT_a + (size_t)512 * 1024, 512, 512, 512, 1024);
  TP(W_Lh, W_Lz, WT_p, 512, 512, 512, 1024);
  TP(W_Lo, nullptr, WT_lo, 10000, 10240, 512, 512);
  TP(W_v, nullptr, WT_v, 512, 512, 512, 512);
  TP(W_init_h, nullptr, WT_i, 512, 512, 512, 512);
  TP(W_init_c, nullptr, WT_i + (size_t)512 * 512, 512, 512, 512, 512);
  conv_pack<<<dim3(4096), dim3(256), 0, stream>>>(enc, enc_p, (long)B_ * L_ * 512 / 8);
  mean_enc<<<dim3(128), dim3(512), 0, stream>>>(enc, mean_b);
  gather_x<<<dim3(T_ * 128), dim3(64), 0, stream>>>(emb, caps, A1);

  // h0 -> A1[0] h-slot (packed bf16), c0 -> cbuf (f32)
  gemm_pk<1, 1, EPI_INIT><<<dim3(8, 16), dim3(256), 0, stream>>>(
      mean_b, WT_i, bix, (void*)A1, nullptr, cbuf, 128, 1024, 512, 0, 0);
  // att_v = enc @ W_v + b_v   (bf16 row-major out)
  gemm_pk<4, 2, EPI_BF16><<<dim3(392, 4), dim3(256), 0, stream>>>(
      enc_p, WT_v, b_v, attv_b, nullptr, nullptr, B_ * L_, 512, 512, 512, 0);

  for (int t = 0; t < T_; t++) {
    bf16* A1t = A1 + (size_t)t * 128 * 1024;
    gemm_pk<1, 1, EPI_F32><<<dim3(8, 40), dim3(256), 0, stream>>>(
        A1t, WT_g, bgx, gatesb, nullptr, nullptr, 128, 2560, 1024, 2560, 0);
    bf16* A1next = (t < T_ - 1) ? (A1 + (size_t)(t + 1) * 128 * 1024) : nullptr;
    lstm_pw<<<dim3(128), dim3(512), 0, stream>>>(gatesb, cbuf, sbuf, A1next, Aag, Aproj);
    gemm_pk<1, 1, EPI_F32><<<dim3(8, 16), dim3(256), 0, stream>>>(
        Aag, WT_a, bax, agswb, nullptr, nullptr, 128, 1024, 1024, 1024, 0);
    att_e<<<dim3(394), dim3(256), 0, stream>>>(attv_b, agswb, w_a, ebuf);
    att_ctx<<<dim3(128, 2), dim3(128), 0, stream>>>(ebuf, enc_p, sbuf, clen,
                                                    alphas, betas, Aproj, t);
    gemm_pk<1, 1, EPI_PROJ><<<dim3(8, 8), dim3(256), 0, stream>>>(
        Aproj, WT_p, bpx, projb, A1t, nullptr, 128, 512, 1024, 0, t * 128);
  }

  // preds = proj_all @ W_Lo + b_Lo  (one big GEMM: 3200 x 10000 x 512)
  gemm_pk<4, 4, EPI_OUT><<<dim3(50, 40), dim3(256), 0, stream>>>(
      projb, WT_lo, b_Lo, preds, nullptr, nullptr, T_ * 128, V_, 512, 0, 0);
}